// Round 6
// baseline (307.582 us; speedup 1.0000x reference)
//
#include <hip/hip_runtime.h>

// PAttention: y = softmax_band(x@Wq^T @ Pk^T * scale) @ Pv, window |l-t|<w.
// L=4096, T=4096, d=2048. Pipeline:
//   k_prep: convert x,Wq,Pk -> bf16; transpose+convert Pv -> Vt (d x T); zero rowsum
//   k1: q = x·Wq^T      (128x128 tile, BK=32, dbuf distance-1 prefetch)
//   k2: P = exp(q·Pk^T·scale) band tiles + fp32 rowsums
//   k3: y = (P·Vt^T)/rowsum over band tiles
// MFMA 16x16x32 bf16 (m89/m91 layouts): A/B frag [idx=lane&15][k=quad*8+e],
// C/D col=lane&15, row=quad*4+reg.
//
// History: R5 dbuf+syncthreads FAILED (drain-0 each iter). R6 counted-vmcnt
// depth-2 FAILED (8 DMA/wave stalls queue; safe depth 4). R7 BK=64/8-wave/
// T2-swizzle WORKED (66->57.3us, conflicts 3.87M->0). R8 static-dbuf FAILED
// (64KB LDS halved residency); its T1 WORKED (FETCH 75->47MB). R9 n64-tile
// k1/k3 FAILED (2x blocks => 2x drains).
//
// R10 (this round): distance-1 prefetch at INVARIANT cost. FETCH(75MB) vs
// staged volume (~490MB) => ~85% of staging is L2-hit (~200-250cy). One
// compute phase (~300cy) of cover hides it. BK 64->32 at 512 thr: STAGE =
// 2 DMA/thread; 2 buffers x 8KB x 2 operands = 32KB LDS (same as R3: 4
// blocks/CU, 32 waves/CU). Per slab: vmcnt(0) [drains s_i, issued one full
// compute earlier] -> barrier -> STAGE(s_{i+1}) -> COMPUTE(s_i). Outstanding
// <= 4. Barrier count unchanged (64/block); ds_read+MFMA totals unchanged;
// compile-time buffer offsets via 2x-unrolled pairs. Safety: crossing
// barrier_i => every wave's slab i-1 MFMAs issued => ds_reads retired =>
// staging that buffer is race-free; vmcnt(0)+barrier => slab i fully in LDS.
// Swizzle (32-col rows): source cb = (l&3)^((l>>3)&3); read col off =
// (quad^((l16>>1)&3))*8 -> exact 2-way = free (m136). T1 kept on k1/k2/k3.

using bf16x8 = __attribute__((ext_vector_type(8))) short;
using f32x4  = __attribute__((ext_vector_type(4))) float;

#define LDIM 4096
#define TDIM 4096
#define DDIM 2048

// u16 elements per LDS buffer half (128 rows x 32 cols = 8KB)
#define HBUF 4096

static __device__ __forceinline__ unsigned short f2bf(float f) {
  union { float f; unsigned u; } c; c.f = f;
  unsigned r = c.u + 0x7FFFu + ((c.u >> 16) & 1u);  // RNE
  return (unsigned short)(r >> 16);
}
static __device__ __forceinline__ unsigned pack2(float a, float b) {
  return (unsigned)f2bf(a) | ((unsigned)f2bf(b) << 16);
}
static __device__ __forceinline__ void gload16(const void* g, void* l) {
  __builtin_amdgcn_global_load_lds((const __attribute__((address_space(1))) void*)g,
                                   (__attribute__((address_space(3))) void*)l, 16, 0, 0);
}

// ---- prep: blocks [0,10240) converts, [10240,12288) Pv transpose, 12288 rowsum ----
__global__ __launch_bounds__(256) void k_prep(const float* __restrict__ x,
                                              const float* __restrict__ Wq,
                                              const float* __restrict__ Pk,
                                              const float* __restrict__ Pv,
                                              unsigned short* __restrict__ xb,
                                              unsigned short* __restrict__ wb,
                                              unsigned short* __restrict__ kb,
                                              unsigned short* __restrict__ vt,
                                              float* __restrict__ rowsum) {
  const int tid = threadIdx.x;
  const int b = blockIdx.x;
  if (b < 10240) {  // elementwise f32 -> bf16, 8 elems/thread
    const float* in; unsigned short* out; size_t i;
    if (b < 4096)      { in = x;  out = xb; i = (size_t)b * 256 + tid; }
    else if (b < 6144) { in = Wq; out = wb; i = (size_t)(b - 4096) * 256 + tid; }
    else               { in = Pk; out = kb; i = (size_t)(b - 6144) * 256 + tid; }
    const float4* p = (const float4*)(in + i * 8);
    float4 a = p[0], c = p[1];
    uint4 o = { pack2(a.x, a.y), pack2(a.z, a.w), pack2(c.x, c.y), pack2(c.z, c.w) };
    *(uint4*)(out + i * 8) = o;
    return;
  }
  if (b == 12288) {
    for (int k = tid; k < LDIM; k += 256) rowsum[k] = 0.f;
    return;
  }
  // Pv (T x D) f32 -> Vt (D x T) bf16, 64x64 tile, transpose in LDS
  __shared__ unsigned short tile[64][72];  // [j_local][t_local], padded
  const int b2 = b - 10240;
  const int t0 = (b2 & 63) * 64, j0 = (b2 >> 6) * 64;
  const int r = tid >> 4, c4 = (tid & 15) * 4;
#pragma unroll
  for (int rr = 0; rr < 64; rr += 16) {
    float4 v = *(const float4*)(Pv + (size_t)(t0 + r + rr) * DDIM + j0 + c4);
    tile[c4 + 0][r + rr] = f2bf(v.x);
    tile[c4 + 1][r + rr] = f2bf(v.y);
    tile[c4 + 2][r + rr] = f2bf(v.z);
    tile[c4 + 3][r + rr] = f2bf(v.w);
  }
  __syncthreads();
  const int jr = tid >> 3, tc = (tid & 7) * 8;
#pragma unroll
  for (int jj = 0; jj < 64; jj += 32)
    *(uint4*)(vt + (size_t)(j0 + jr + jj) * TDIM + t0 + tc) =
        *(const uint4*)&tile[jr + jj][tc];
}

// ---- 128x128 tile, BK=32, 8-wave (2Mx4N), dbuf distance-1 prefetch K-loop ----
// LDS: per operand 2 buffers of 128 rows x 32 u16. Staged linearly by
// global_load_lds (lane l -> row w*16+(l>>2), phys col-block l&3); swizzle on
// the global SOURCE (rule #21): logical cb = (l&3)^((l>>3)&3). Frag read at
// phys cb = quad^((l16>>1)&3) -> 2-way bank aliasing = free.
static __device__ __forceinline__ void gemm_loop(const unsigned short* __restrict__ A,
                                                 const unsigned short* __restrict__ B,
                                                 int m0, int n0, long lda, long ldb,
                                                 int kbeg, int kend,
                                                 unsigned short* As, unsigned short* Bs,
                                                 f32x4 (&acc)[4][2]) {
  const int tid = threadIdx.x;
  const int wave = tid >> 6, lane = tid & 63;
  const int quad = lane >> 4, l16 = lane & 15;
  const int wm = wave >> 2, wn = wave & 3;
  const int srow = wave * 16 + (lane >> 2);            // staged row (of 128)
  const int scb  = (lane & 3) ^ ((lane >> 3) & 3);     // inverse-swizzled src col-block

  const unsigned short* gA = A + (long)(m0 + srow) * lda + scb * 8;
  const unsigned short* gB = B + (long)(n0 + srow) * ldb + scb * 8;
  unsigned short* lA = As + wave * 512;  // u16: wave region = 16 rows x 32
  unsigned short* lB = Bs + wave * 512;

  const int kx = (quad ^ ((l16 >> 1) & 3)) * 8;        // frag-read swizzled col (u16)

#define STAGE(k0, bo) do {                 \
    gload16(gA + (k0), lA + (bo));         \
    gload16(gB + (k0), lB + (bo)); } while (0)

#define COMPUTE(bo) do {                                                           \
    bf16x8 af[4], bfr[2];                                                          \
    _Pragma("unroll")                                                              \
    for (int i = 0; i < 4; i++)                                                    \
      af[i] = *(const bf16x8*)&As[(bo) + (wm * 64 + i * 16 + l16) * 32 + kx];      \
    _Pragma("unroll")                                                              \
    for (int j = 0; j < 2; j++)                                                    \
      bfr[j] = *(const bf16x8*)&Bs[(bo) + (wn * 32 + j * 16 + l16) * 32 + kx];     \
    _Pragma("unroll")                                                              \
    for (int i = 0; i < 4; i++)                                                    \
      _Pragma("unroll")                                                            \
      for (int j = 0; j < 2; j++)                                                  \
        acc[i][j] = __builtin_amdgcn_mfma_f32_16x16x32_bf16(af[i], bfr[j],         \
                                                            acc[i][j], 0, 0, 0);   \
  } while (0)

  // prologue: slab 0 -> buf0
  STAGE(kbeg, 0);
  const int np = (kend - kbeg) >> 6;  // pairs of BK32 slabs; always >= 9 here
  int k0 = kbeg;
  for (int p = 0; p < np - 1; ++p, k0 += 64) {
    asm volatile("s_waitcnt vmcnt(0)" ::: "memory");  // s_even landed (1 compute of cover)
    __builtin_amdgcn_s_barrier();
    STAGE(k0 + 32, HBUF);                             // next slab -> buf1
    COMPUTE(0);
    asm volatile("s_waitcnt vmcnt(0)" ::: "memory");  // s_odd landed
    __builtin_amdgcn_s_barrier();
    STAGE(k0 + 64, 0);                                // next slab -> buf0
    COMPUTE(HBUF);
  }
  // last pair: no stage after the final slab
  asm volatile("s_waitcnt vmcnt(0)" ::: "memory");
  __builtin_amdgcn_s_barrier();
  STAGE(k0 + 32, HBUF);
  COMPUTE(0);
  asm volatile("s_waitcnt vmcnt(0)" ::: "memory");
  __builtin_amdgcn_s_barrier();
  COMPUTE(HBUF);
#undef STAGE
#undef COMPUTE
}

// ---------------- K1: q = x · Wq^T  (bf16 out) ----------------
__global__ __launch_bounds__(512) void k1_qgemm(const unsigned short* __restrict__ X,
                                                const unsigned short* __restrict__ W,
                                                unsigned short* __restrict__ q) {
  __shared__ __align__(16) unsigned short As[2 * HBUF];
  __shared__ __align__(16) unsigned short Bs[2 * HBUF];
  // T1 bijective XCD swizzle: nwg = 16*32 = 512, %8 == 0
  const unsigned flat = blockIdx.y * 16 + blockIdx.x;
  const unsigned swz = (flat & 7) * 64 + (flat >> 3);
  const int bx = swz & 15, by = swz >> 4;
  f32x4 acc[4][2] = {};
  const int m0 = by * 128, n0 = bx * 128;
  gemm_loop(X, W, m0, n0, DDIM, DDIM, 0, DDIM, As, Bs, acc);
  const int tid = threadIdx.x;
  const int wave = tid >> 6, lane = tid & 63;
  const int quad = lane >> 4, l16 = lane & 15, wm = wave >> 2, wn = wave & 3;
#pragma unroll
  for (int i = 0; i < 4; i++)
#pragma unroll
    for (int j = 0; j < 2; j++)
#pragma unroll
      for (int r = 0; r < 4; r++) {
        int row = m0 + wm * 64 + i * 16 + quad * 4 + r;
        int col = n0 + wn * 32 + j * 16 + l16;
        q[(long)row * DDIM + col] = f2bf(acc[i][j][r]);
      }
}

// ------------- K2: banded P = exp(q·Pk^T·scale), rowsums -------------
__global__ __launch_bounds__(512) void k2_qk(const unsigned short* __restrict__ Q,
                                             const unsigned short* __restrict__ Kb,
                                             unsigned short* __restrict__ P,
                                             float* __restrict__ rowsum,
                                             const int* __restrict__ wptr) {
  // T1 bijective XCD swizzle: nwg = 32*32 = 1024, %8 == 0
  const unsigned flat = blockIdx.y * 32 + blockIdx.x;
  const unsigned swz = (flat & 7) * 128 + (flat >> 3);
  const int bx = swz & 31, by = swz >> 5;
  const int w = *wptr;
  const int l0 = by * 128, t0 = bx * 128;
  int lo = l0 - w + 1; if (lo < 0) lo = 0;
  int hi = l0 + 127 + w - 1; if (hi > TDIM - 1) hi = TDIM - 1;
  if (bx < (lo >> 7) || bx > (hi >> 7)) return;  // uniform
  __shared__ __align__(16) unsigned short As[2 * HBUF];
  __shared__ __align__(16) unsigned short Bs[2 * HBUF];
  f32x4 acc[4][2] = {};
  gemm_loop(Q, Kb, l0, t0, DDIM, DDIM, 0, DDIM, As, Bs, acc);
  const float scale = 0.022097086912079608f;  // 1/sqrt(2048)
  const int tid = threadIdx.x;
  const int wave = tid >> 6, lane = tid & 63;
  const int quad = lane >> 4, l16 = lane & 15, wm = wave >> 2, wn = wave & 3;
#pragma unroll
  for (int i = 0; i < 4; i++) {
    float rs[4] = {0.f, 0.f, 0.f, 0.f};
#pragma unroll
    for (int j = 0; j < 2; j++)
#pragma unroll
      for (int r = 0; r < 4; r++) {
        int l = l0 + wm * 64 + i * 16 + quad * 4 + r;
        int t = t0 + wn * 32 + j * 16 + l16;
        int dlt = l - t; dlt = dlt < 0 ? -dlt : dlt;
        float e = 0.f;
        // scores ~ N(0,1): no overflow -> max-free softmax is exact math
        if (dlt < w) e = __expf(acc[i][j][r] * scale);
        unsigned short bv = f2bf(e);
        P[(long)l * TDIM + t] = bv;
        rs[r] += __uint_as_float((unsigned)bv << 16);  // sum stored (rounded) values
      }
#pragma unroll
    for (int r = 0; r < 4; ++r) {
      float s = rs[r];
      s += __shfl_xor(s, 1);
      s += __shfl_xor(s, 2);
      s += __shfl_xor(s, 4);
      s += __shfl_xor(s, 8);  // 16 lanes hold this row's 32-col slice
      if (l16 == 0) atomicAdd(&rowsum[l0 + wm * 64 + i * 16 + quad * 4 + r], s);
    }
  }
}

// ---------------- K3: y = (P · Vt^T) / rowsum over band tiles ----------------
__global__ __launch_bounds__(512) void k3_pv(const unsigned short* __restrict__ P,
                                             const unsigned short* __restrict__ Vt,
                                             const float* __restrict__ rowsum,
                                             float* __restrict__ Y,
                                             const int* __restrict__ wptr) {
  // T1 bijective XCD swizzle: nwg = 16*32 = 512, %8 == 0
  const unsigned flat = blockIdx.y * 16 + blockIdx.x;
  const unsigned swz = (flat & 7) * 64 + (flat >> 3);
  const int bx = swz & 15, by = swz >> 4;
  const int w = *wptr;
  const int l0 = by * 128, j0 = bx * 128;
  int lo = l0 - w + 1; if (lo < 0) lo = 0;
  int hi = l0 + 127 + w - 1; if (hi > TDIM - 1) hi = TDIM - 1;
  const int kb = (lo >> 7) * 128, ke = ((hi >> 7) + 1) * 128;  // exactly K2's tiles
  __shared__ __align__(16) unsigned short As[2 * HBUF];
  __shared__ __align__(16) unsigned short Bs[2 * HBUF];
  f32x4 acc[4][2] = {};
  gemm_loop(P, Vt, l0, j0, TDIM, TDIM, kb, ke, As, Bs, acc);
  const int tid = threadIdx.x;
  const int wave = tid >> 6, lane = tid & 63;
  const int quad = lane >> 4, l16 = lane & 15, wm = wave >> 2, wn = wave & 3;
#pragma unroll
  for (int i = 0; i < 4; i++)
#pragma unroll
    for (int r = 0; r < 4; r++) {
      const int l = l0 + wm * 64 + i * 16 + quad * 4 + r;
      const float inv = 1.0f / rowsum[l];
#pragma unroll
      for (int j = 0; j < 2; j++)
        Y[(long)l * DDIM + j0 + wn * 32 + j * 16 + l16] = acc[i][j][r] * inv;
    }
}

extern "C" void kernel_launch(void* const* d_in, const int* in_sizes, int n_in,
                              void* d_out, int out_size, void* d_ws, size_t ws_size,
                              hipStream_t stream) {
  const float* x  = (const float*)d_in[0];   // (4096, 2048)
  const float* Wq = (const float*)d_in[1];   // (2048, 2048)
  const float* Pk = (const float*)d_in[2];   // (1, 4096, 2048)
  const float* Pv = (const float*)d_in[3];   // (1, 4096, 2048)
  const int* wptr = (const int*)d_in[4];     // sliding_window_size
  float* Y = (float*)d_out;                  // (1, 4096, 2048) f32

  // ws (u16 elems). P aliases xb+wb (dead after K1). Total ~84 MB.
  unsigned short* base = (unsigned short*)d_ws;
  unsigned short* Pm = base;                          // 4096*4096 [k2/k3]
  unsigned short* xb = base;                          // 4096*2048 (aliases Pm)
  unsigned short* wb = base + (size_t)LDIM * DDIM;    // 2048*2048 (aliases Pm)
  unsigned short* kb = base + (size_t)TDIM * TDIM;    // 4096*2048
  unsigned short* vt = kb + (size_t)TDIM * DDIM;      // 2048*4096
  unsigned short* qb = vt + (size_t)DDIM * TDIM;      // 4096*2048
  float* rowsum = (float*)(qb + (size_t)LDIM * DDIM); // 4096 f32

  k_prep<<<12289, 256, 0, stream>>>(x, Wq, Pk, Pv, xb, wb, kb, vt, rowsum);
  k1_qgemm<<<dim3(DDIM / 128, LDIM / 128), 512, 0, stream>>>(xb, wb, qb);
  k2_qk<<<dim3(TDIM / 128, LDIM / 128), 512, 0, stream>>>(qb, kb, Pm, rowsum, wptr);
  k3_pv<<<dim3(DDIM / 128, LDIM / 128), 512, 0, stream>>>(Pm, vt, rowsum, Y, wptr);
}

// Round 7
// 283.868 us; speedup vs baseline: 1.0835x; 1.0835x over previous
//
#include <hip/hip_runtime.h>

// PAttention: y = softmax_band(x@Wq^T @ Pk^T * scale) @ Pv, window |l-t|<w.
// L=4096, T=4096, d=2048. Pipeline:
//   k_prep: convert x,Wq,Pk -> bf16; transpose+convert Pv -> Vt (d x T); zero rowsum
//   k1: q = x·Wq^T      (128x128 tile, BK=64, 1024 threads / 16 waves)
//   k2: P = exp(q·Pk^T·scale) band tiles + fp32 rowsums (512 thr, R3-exact)
//   k3: y = (P·Vt^T)/rowsum over band tiles (1024 threads / 16 waves)
// MFMA 16x16x32 bf16 (m89/m91): A/B frag [idx=lane&15][k=quad*8+e],
// C/D col=lane&15, row=quad*4+reg.
//
// History (what the data supports):
//  - R3 structure (BK=64, single-buffer 2-barrier, both-sides XOR swizzle) is
//    the best loop: k2=57.3us @ 4 blocks/CU. Total 279.
//  - Intra-block pipelining: 0-for-4 (R5 dbuf, R6 vmcnt-depth2, R8 static dbuf,
//    R10 distance-1). Every variant <= R3. Do not retry at source level.
//  - T1 XCD swizzle on k2: FETCH 75->46MB but time +4.5us (latency-bound, HBM
//    bytes don't price in). Reverted.
//  - Fill is the lever: time tracks waves/CU during barrier drains. k2 @ 32
//    waves/CU = 57us; k1/k3 @ 16 waves/CU = ~85-90us each for the same FLOPs.
//
// R11 (this round): k1/k3 -> 1024-thread blocks. Same 128x128 tile, same BK=64
// 2-barrier loop, same swizzle; 16 waves as 4Mx4N (32x32/wave, acc[2][2]).
// Grid stays 512 = 2 blocks/CU but 32 waves/CU (= cap, = k2's fill). Per-slab
// staging: each wave 8 rows of A + 8 of B = 2 DMA/thread. Total drains/traffic/
// ds_reads/MFMA unchanged vs R3. __launch_bounds__(1024,8) pins <=64 VGPR so
// both blocks are truly resident (frag footprint ~48 regs, should not spill).

using bf16x8 = __attribute__((ext_vector_type(8))) short;
using f32x4  = __attribute__((ext_vector_type(4))) float;

#define LDIM 4096
#define TDIM 4096
#define DDIM 2048

static __device__ __forceinline__ unsigned short f2bf(float f) {
  union { float f; unsigned u; } c; c.f = f;
  unsigned r = c.u + 0x7FFFu + ((c.u >> 16) & 1u);  // RNE
  return (unsigned short)(r >> 16);
}
static __device__ __forceinline__ unsigned pack2(float a, float b) {
  return (unsigned)f2bf(a) | ((unsigned)f2bf(b) << 16);
}
static __device__ __forceinline__ void gload16(const void* g, void* l) {
  __builtin_amdgcn_global_load_lds((const __attribute__((address_space(1))) void*)g,
                                   (__attribute__((address_space(3))) void*)l, 16, 0, 0);
}

// ---- prep: blocks [0,10240) converts, [10240,12288) Pv transpose, 12288 rowsum ----
__global__ __launch_bounds__(256) void k_prep(const float* __restrict__ x,
                                              const float* __restrict__ Wq,
                                              const float* __restrict__ Pk,
                                              const float* __restrict__ Pv,
                                              unsigned short* __restrict__ xb,
                                              unsigned short* __restrict__ wb,
                                              unsigned short* __restrict__ kb,
                                              unsigned short* __restrict__ vt,
                                              float* __restrict__ rowsum) {
  const int tid = threadIdx.x;
  const int b = blockIdx.x;
  if (b < 10240) {  // elementwise f32 -> bf16, 8 elems/thread
    const float* in; unsigned short* out; size_t i;
    if (b < 4096)      { in = x;  out = xb; i = (size_t)b * 256 + tid; }
    else if (b < 6144) { in = Wq; out = wb; i = (size_t)(b - 4096) * 256 + tid; }
    else               { in = Pk; out = kb; i = (size_t)(b - 6144) * 256 + tid; }
    const float4* p = (const float4*)(in + i * 8);
    float4 a = p[0], c = p[1];
    uint4 o = { pack2(a.x, a.y), pack2(a.z, a.w), pack2(c.x, c.y), pack2(c.z, c.w) };
    *(uint4*)(out + i * 8) = o;
    return;
  }
  if (b == 12288) {
    for (int k = tid; k < LDIM; k += 256) rowsum[k] = 0.f;
    return;
  }
  // Pv (T x D) f32 -> Vt (D x T) bf16, 64x64 tile, transpose in LDS
  __shared__ unsigned short tile[64][72];  // [j_local][t_local], padded
  const int b2 = b - 10240;
  const int t0 = (b2 & 63) * 64, j0 = (b2 >> 6) * 64;
  const int r = tid >> 4, c4 = (tid & 15) * 4;
#pragma unroll
  for (int rr = 0; rr < 64; rr += 16) {
    float4 v = *(const float4*)(Pv + (size_t)(t0 + r + rr) * DDIM + j0 + c4);
    tile[c4 + 0][r + rr] = f2bf(v.x);
    tile[c4 + 1][r + rr] = f2bf(v.y);
    tile[c4 + 2][r + rr] = f2bf(v.z);
    tile[c4 + 3][r + rr] = f2bf(v.w);
  }
  __syncthreads();
  const int jr = tid >> 3, tc = (tid & 7) * 8;
#pragma unroll
  for (int jj = 0; jj < 64; jj += 32)
    *(uint4*)(vt + (size_t)(j0 + jr + jj) * TDIM + t0 + tc) =
        *(const uint4*)&tile[jr + jj][tc];
}

// ---- 128x128 tile, BK=64, 8-wave (2Mx4N), single-buffer 2-barrier K-loop (R3) ----
// LDS tile: 128 rows x 64 u16, phys = row*64 + (cb ^ (row&7))*8  (u16 units).
// Staged linearly by global_load_lds; swizzle applied to the global SOURCE.
static __device__ __forceinline__ void gemm_loop8(const unsigned short* __restrict__ A,
                                                  const unsigned short* __restrict__ B,
                                                  int m0, int n0, long lda, long ldb,
                                                  int kbeg, int kend,
                                                  unsigned short* As, unsigned short* Bs,
                                                  f32x4 (&acc)[4][2]) {
  const int tid = threadIdx.x;
  const int wave = tid >> 6, lane = tid & 63;
  const int quad = lane >> 4, l16 = lane & 15;
  const int wm = wave >> 2, wn = wave & 3;
  const int srow = wave * 16 + (lane >> 3);       // staged row (half t adds +8)
  const int scb  = (lane & 7) ^ (lane >> 3);      // inverse-swizzled source col-block

  const unsigned short* gA = A + (long)(m0 + srow) * lda + scb * 8;
  const unsigned short* gB = B + (long)(n0 + srow) * ldb + scb * 8;
  unsigned short* lA = As + wave * 1024;  // u16: wave region = 16 rows = 2KB
  unsigned short* lB = Bs + wave * 1024;

  const int sw = (l16 & 7) * 8;  // frag-read swizzle (u16 units)

  for (int k0 = kbeg; k0 < kend; k0 += 64) {
    gload16(gA + k0,           lA);        // rows w*16 .. w*16+7
    gload16(gA + k0 + 8 * lda, lA + 512);  // rows w*16+8 .. w*16+15
    gload16(gB + k0,           lB);
    gload16(gB + k0 + 8 * ldb, lB + 512);
    __syncthreads();
    bf16x8 af[4][2], bfr[2][2];
#pragma unroll
    for (int i = 0; i < 4; i++)
#pragma unroll
      for (int h = 0; h < 2; h++)
        af[i][h] = *(const bf16x8*)&As[(wm * 64 + i * 16 + l16) * 64 +
                                       (((h * 4 + quad) * 8) ^ sw)];
#pragma unroll
    for (int j = 0; j < 2; j++)
#pragma unroll
      for (int h = 0; h < 2; h++)
        bfr[j][h] = *(const bf16x8*)&Bs[(wn * 32 + j * 16 + l16) * 64 +
                                        (((h * 4 + quad) * 8) ^ sw)];
#pragma unroll
    for (int h = 0; h < 2; h++)
#pragma unroll
      for (int i = 0; i < 4; i++)
#pragma unroll
        for (int j = 0; j < 2; j++)
          acc[i][j] = __builtin_amdgcn_mfma_f32_16x16x32_bf16(af[i][h], bfr[j][h],
                                                              acc[i][j], 0, 0, 0);
    __syncthreads();
  }
}

// ---- 128x128 tile, BK=64, 16-wave (4Mx4N, 32x32/wave), same 2-barrier loop ----
// Each wave stages 8 rows of A and 8 rows of B (2 DMA/thread). Same LDS layout
// and swizzle as gemm_loop8.
static __device__ __forceinline__ void gemm_loop16(const unsigned short* __restrict__ A,
                                                   const unsigned short* __restrict__ B,
                                                   int m0, int n0, long lda, long ldb,
                                                   int kbeg, int kend,
                                                   unsigned short* As, unsigned short* Bs,
                                                   f32x4 (&acc)[2][2]) {
  const int tid = threadIdx.x;
  const int wave = tid >> 6, lane = tid & 63;      // wave 0..15
  const int quad = lane >> 4, l16 = lane & 15;
  const int wm = wave >> 2, wn = wave & 3;         // 4x4 wave grid, 32x32 each
  const int srow = wave * 8 + (lane >> 3);         // staged row (of 128)
  const int scb  = (lane & 7) ^ (lane >> 3);       // inverse-swizzled source col-block

  const unsigned short* gA = A + (long)(m0 + srow) * lda + scb * 8;
  const unsigned short* gB = B + (long)(n0 + srow) * ldb + scb * 8;
  unsigned short* lA = As + wave * 512;  // u16: wave region = 8 rows = 1KB
  unsigned short* lB = Bs + wave * 512;

  const int sw = (l16 & 7) * 8;  // frag-read swizzle (u16 units)

  for (int k0 = kbeg; k0 < kend; k0 += 64) {
    gload16(gA + k0, lA);        // rows w*8 .. w*8+7
    gload16(gB + k0, lB);
    __syncthreads();
    bf16x8 af[2][2], bfr[2][2];
#pragma unroll
    for (int i = 0; i < 2; i++)
#pragma unroll
      for (int h = 0; h < 2; h++)
        af[i][h] = *(const bf16x8*)&As[(wm * 32 + i * 16 + l16) * 64 +
                                       (((h * 4 + quad) * 8) ^ sw)];
#pragma unroll
    for (int j = 0; j < 2; j++)
#pragma unroll
      for (int h = 0; h < 2; h++)
        bfr[j][h] = *(const bf16x8*)&Bs[(wn * 32 + j * 16 + l16) * 64 +
                                        (((h * 4 + quad) * 8) ^ sw)];
#pragma unroll
    for (int h = 0; h < 2; h++)
#pragma unroll
      for (int i = 0; i < 2; i++)
#pragma unroll
        for (int j = 0; j < 2; j++)
          acc[i][j] = __builtin_amdgcn_mfma_f32_16x16x32_bf16(af[i][h], bfr[j][h],
                                                              acc[i][j], 0, 0, 0);
    __syncthreads();
  }
}

// ---------------- K1: q = x · Wq^T  (bf16 out), 1024 threads ----------------
__global__ __launch_bounds__(1024, 8) void k1_qgemm(const unsigned short* __restrict__ X,
                                                    const unsigned short* __restrict__ W,
                                                    unsigned short* __restrict__ q) {
  __shared__ __align__(16) unsigned short As[128 * 64];
  __shared__ __align__(16) unsigned short Bs[128 * 64];
  f32x4 acc[2][2] = {};
  const int m0 = blockIdx.y * 128, n0 = blockIdx.x * 128;
  gemm_loop16(X, W, m0, n0, DDIM, DDIM, 0, DDIM, As, Bs, acc);
  const int tid = threadIdx.x;
  const int wave = tid >> 6, lane = tid & 63;
  const int quad = lane >> 4, l16 = lane & 15, wm = wave >> 2, wn = wave & 3;
#pragma unroll
  for (int i = 0; i < 2; i++)
#pragma unroll
    for (int j = 0; j < 2; j++)
#pragma unroll
      for (int r = 0; r < 4; r++) {
        int row = m0 + wm * 32 + i * 16 + quad * 4 + r;
        int col = n0 + wn * 32 + j * 16 + l16;
        q[(long)row * DDIM + col] = f2bf(acc[i][j][r]);
      }
}

// ------------- K2: banded P = exp(q·Pk^T·scale), rowsums (R3-exact) -------------
__global__ __launch_bounds__(512) void k2_qk(const unsigned short* __restrict__ Q,
                                             const unsigned short* __restrict__ Kb,
                                             unsigned short* __restrict__ P,
                                             float* __restrict__ rowsum,
                                             const int* __restrict__ wptr) {
  const int w = *wptr;
  const int l0 = blockIdx.y * 128, t0 = blockIdx.x * 128;
  int lo = l0 - w + 1; if (lo < 0) lo = 0;
  int hi = l0 + 127 + w - 1; if (hi > TDIM - 1) hi = TDIM - 1;
  if ((int)blockIdx.x < (lo >> 7) || (int)blockIdx.x > (hi >> 7)) return;  // uniform
  __shared__ __align__(16) unsigned short As[128 * 64];
  __shared__ __align__(16) unsigned short Bs[128 * 64];
  f32x4 acc[4][2] = {};
  gemm_loop8(Q, Kb, l0, t0, DDIM, DDIM, 0, DDIM, As, Bs, acc);
  const float scale = 0.022097086912079608f;  // 1/sqrt(2048)
  const int tid = threadIdx.x;
  const int wave = tid >> 6, lane = tid & 63;
  const int quad = lane >> 4, l16 = lane & 15, wm = wave >> 2, wn = wave & 3;
#pragma unroll
  for (int i = 0; i < 4; i++) {
    float rs[4] = {0.f, 0.f, 0.f, 0.f};
#pragma unroll
    for (int j = 0; j < 2; j++)
#pragma unroll
      for (int r = 0; r < 4; r++) {
        int l = l0 + wm * 64 + i * 16 + quad * 4 + r;
        int t = t0 + wn * 32 + j * 16 + l16;
        int dlt = l - t; dlt = dlt < 0 ? -dlt : dlt;
        float e = 0.f;
        // scores ~ N(0,1): no overflow -> max-free softmax is exact math
        if (dlt < w) e = __expf(acc[i][j][r] * scale);
        unsigned short bv = f2bf(e);
        P[(long)l * TDIM + t] = bv;
        rs[r] += __uint_as_float((unsigned)bv << 16);  // sum stored (rounded) values
      }
#pragma unroll
    for (int r = 0; r < 4; ++r) {
      float s = rs[r];
      s += __shfl_xor(s, 1);
      s += __shfl_xor(s, 2);
      s += __shfl_xor(s, 4);
      s += __shfl_xor(s, 8);  // 16 lanes hold this row's 32-col slice
      if (l16 == 0) atomicAdd(&rowsum[l0 + wm * 64 + i * 16 + quad * 4 + r], s);
    }
  }
}

// ---------------- K3: y = (P · Vt^T) / rowsum, 1024 threads ----------------
__global__ __launch_bounds__(1024, 8) void k3_pv(const unsigned short* __restrict__ P,
                                                 const unsigned short* __restrict__ Vt,
                                                 const float* __restrict__ rowsum,
                                                 float* __restrict__ Y,
                                                 const int* __restrict__ wptr) {
  const int w = *wptr;
  const int l0 = blockIdx.y * 128, j0 = blockIdx.x * 128;
  int lo = l0 - w + 1; if (lo < 0) lo = 0;
  int hi = l0 + 127 + w - 1; if (hi > TDIM - 1) hi = TDIM - 1;
  const int kb = (lo >> 7) * 128, ke = ((hi >> 7) + 1) * 128;  // exactly K2's tiles
  __shared__ __align__(16) unsigned short As[128 * 64];
  __shared__ __align__(16) unsigned short Bs[128 * 64];
  f32x4 acc[2][2] = {};
  gemm_loop16(P, Vt, l0, j0, TDIM, TDIM, kb, ke, As, Bs, acc);
  const int tid = threadIdx.x;
  const int wave = tid >> 6, lane = tid & 63;
  const int quad = lane >> 4, l16 = lane & 15, wm = wave >> 2, wn = wave & 3;
#pragma unroll
  for (int i = 0; i < 2; i++)
#pragma unroll
    for (int r = 0; r < 4; r++) {
      const int l = l0 + wm * 32 + i * 16 + quad * 4 + r;
      const float inv = 1.0f / rowsum[l];
#pragma unroll
      for (int j = 0; j < 2; j++)
        Y[(long)l * DDIM + j0 + wn * 32 + j * 16 + l16] = acc[i][j][r] * inv;
    }
}

extern "C" void kernel_launch(void* const* d_in, const int* in_sizes, int n_in,
                              void* d_out, int out_size, void* d_ws, size_t ws_size,
                              hipStream_t stream) {
  const float* x  = (const float*)d_in[0];   // (4096, 2048)
  const float* Wq = (const float*)d_in[1];   // (2048, 2048)
  const float* Pk = (const float*)d_in[2];   // (1, 4096, 2048)
  const float* Pv = (const float*)d_in[3];   // (1, 4096, 2048)
  const int* wptr = (const int*)d_in[4];     // sliding_window_size
  float* Y = (float*)d_out;                  // (1, 4096, 2048) f32

  // ws (u16 elems). P aliases xb+wb (dead after K1). Total ~84 MB.
  unsigned short* base = (unsigned short*)d_ws;
  unsigned short* Pm = base;                          // 4096*4096 [k2/k3]
  unsigned short* xb = base;                          // 4096*2048 (aliases Pm)
  unsigned short* wb = base + (size_t)LDIM * DDIM;    // 2048*2048 (aliases Pm)
  unsigned short* kb = base + (size_t)TDIM * TDIM;    // 4096*2048
  unsigned short* vt = kb + (size_t)TDIM * DDIM;      // 2048*4096
  unsigned short* qb = vt + (size_t)DDIM * TDIM;      // 4096*2048
  float* rowsum = (float*)(qb + (size_t)LDIM * DDIM); // 4096 f32

  k_prep<<<12289, 256, 0, stream>>>(x, Wq, Pk, Pv, xb, wb, kb, vt, rowsum);
  k1_qgemm<<<dim3(DDIM / 128, LDIM / 128), 1024, 0, stream>>>(xb, wb, qb);
  k2_qk<<<dim3(TDIM / 128, LDIM / 128), 512, 0, stream>>>(qb, kb, Pm, rowsum, wptr);
  k3_pv<<<dim3(DDIM / 128, LDIM / 128), 1024, 0, stream>>>(Pm, vt, rowsum, Y, wptr);
}

// Round 8
// 270.710 us; speedup vs baseline: 1.1362x; 1.0486x over previous
//
#include <hip/hip_runtime.h>

// PAttention: y = softmax_band(x@Wq^T @ Pk^T * scale) @ Pv, window |l-t|<w.
// L=4096, T=4096, d=2048. Pipeline (R12):
//   k_prep:   convert x,Wq -> bf16 (k1's only real dependencies)
//   k1_fused: blocks [0,512) = q = x·Wq^T (R3-exact GEMM);
//             blocks [512,2560) = Pk f32->bf16; [2560,4608) = Pv transpose -> Vt;
//             block 4608 = zero rowsum.  Prep work co-schedules in k1's idle
//             wave slots (2 GEMM blocks/CU leave 2 of 4 block slots free) and
//             idle BW (~20% HBM) -> ~96MB of prep traffic hidden under the GEMM.
//   k2: P = exp(q·Pk^T·scale) band tiles + fp32 rowsums (R3-exact, proven 57.4us)
//   k3: y = (P·Vt^T)/rowsum over band tiles (R3-exact)
// MFMA 16x16x32 bf16 (m89/m91): A/B frag [idx=lane&15][k=quad*8+e],
// C/D col=lane&15, row=quad*4+reg.
//
// History (what 8 rounds of data support):
//  - R3 structure (BK=64, 8-wave, single-buffer 2-barrier, both-sides XOR
//    swizzle, 4 DMA/thread) is the optimum GEMM loop: k2=57.4us, total 278.9.
//  - Intra-block pipelining: 0-for-4 (dbuf, vmcnt-depth2, static-dbuf,
//    distance-1). All <= R3. Do not retry at source level.
//  - Tile/wave reshapes: 0-for-3 (n64 tiles, 1024-thr, 256-thr). Wash or worse.
//  - T1 XCD swizzle: FETCH 75->46MB but time +4.5us (latency-bound; HBM bytes
//    don't price in). Reverted.
//  - This round attacks the serial-prep budget instead of the GEMM engine.

using bf16x8 = __attribute__((ext_vector_type(8))) short;
using f32x4  = __attribute__((ext_vector_type(4))) float;

#define LDIM 4096
#define TDIM 4096
#define DDIM 2048

static __device__ __forceinline__ unsigned short f2bf(float f) {
  union { float f; unsigned u; } c; c.f = f;
  unsigned r = c.u + 0x7FFFu + ((c.u >> 16) & 1u);  // RNE
  return (unsigned short)(r >> 16);
}
static __device__ __forceinline__ unsigned pack2(float a, float b) {
  return (unsigned)f2bf(a) | ((unsigned)f2bf(b) << 16);
}
static __device__ __forceinline__ void gload16(const void* g, void* l) {
  __builtin_amdgcn_global_load_lds((const __attribute__((address_space(1))) void*)g,
                                   (__attribute__((address_space(3))) void*)l, 16, 0, 0);
}

// ---- prep: x,Wq f32 -> bf16 only (6144 blocks @ 256 thr) ----
__global__ __launch_bounds__(256) void k_prep(const float* __restrict__ x,
                                              const float* __restrict__ Wq,
                                              unsigned short* __restrict__ xb,
                                              unsigned short* __restrict__ wb) {
  const int tid = threadIdx.x;
  const int b = blockIdx.x;
  const float* in; unsigned short* out; size_t i;
  if (b < 4096) { in = x;  out = xb; i = (size_t)b * 256 + tid; }
  else          { in = Wq; out = wb; i = (size_t)(b - 4096) * 256 + tid; }
  const float4* p = (const float4*)(in + i * 8);
  float4 a = p[0], c = p[1];
  uint4 o = { pack2(a.x, a.y), pack2(a.z, a.w), pack2(c.x, c.y), pack2(c.z, c.w) };
  *(uint4*)(out + i * 8) = o;
}

// ---- 128x128 tile, BK=64, 8-wave (2Mx4N), single-buffer 2-barrier K-loop (R3) ----
// LDS tile: 128 rows x 64 u16, phys = row*64 + (cb ^ (row&7))*8  (u16 units).
// Staged linearly by global_load_lds; swizzle applied to the global SOURCE.
static __device__ __forceinline__ void gemm_loop8(const unsigned short* __restrict__ A,
                                                  const unsigned short* __restrict__ B,
                                                  int m0, int n0, long lda, long ldb,
                                                  int kbeg, int kend,
                                                  unsigned short* As, unsigned short* Bs,
                                                  f32x4 (&acc)[4][2]) {
  const int tid = threadIdx.x;
  const int wave = tid >> 6, lane = tid & 63;
  const int quad = lane >> 4, l16 = lane & 15;
  const int wm = wave >> 2, wn = wave & 3;
  const int srow = wave * 16 + (lane >> 3);       // staged row (half t adds +8)
  const int scb  = (lane & 7) ^ (lane >> 3);      // inverse-swizzled source col-block

  const unsigned short* gA = A + (long)(m0 + srow) * lda + scb * 8;
  const unsigned short* gB = B + (long)(n0 + srow) * ldb + scb * 8;
  unsigned short* lA = As + wave * 1024;  // u16: wave region = 16 rows = 2KB
  unsigned short* lB = Bs + wave * 1024;

  const int sw = (l16 & 7) * 8;  // frag-read swizzle (u16 units)

  for (int k0 = kbeg; k0 < kend; k0 += 64) {
    gload16(gA + k0,           lA);        // rows w*16 .. w*16+7
    gload16(gA + k0 + 8 * lda, lA + 512);  // rows w*16+8 .. w*16+15
    gload16(gB + k0,           lB);
    gload16(gB + k0 + 8 * ldb, lB + 512);
    __syncthreads();
    bf16x8 af[4][2], bfr[2][2];
#pragma unroll
    for (int i = 0; i < 4; i++)
#pragma unroll
      for (int h = 0; h < 2; h++)
        af[i][h] = *(const bf16x8*)&As[(wm * 64 + i * 16 + l16) * 64 +
                                       (((h * 4 + quad) * 8) ^ sw)];
#pragma unroll
    for (int j = 0; j < 2; j++)
#pragma unroll
      for (int h = 0; h < 2; h++)
        bfr[j][h] = *(const bf16x8*)&Bs[(wn * 32 + j * 16 + l16) * 64 +
                                        (((h * 4 + quad) * 8) ^ sw)];
#pragma unroll
    for (int h = 0; h < 2; h++)
#pragma unroll
      for (int i = 0; i < 4; i++)
#pragma unroll
        for (int j = 0; j < 2; j++)
          acc[i][j] = __builtin_amdgcn_mfma_f32_16x16x32_bf16(af[i][h], bfr[j][h],
                                                              acc[i][j], 0, 0, 0);
    __syncthreads();
  }
}

// ---- K1 fused: [0,512) q-GEMM (R3) | [512,2560) Pk cvt | [2560,4608) Pv^T | 4608 zero ----
__global__ __launch_bounds__(512) void k1_fused(const unsigned short* __restrict__ X,
                                                const unsigned short* __restrict__ W,
                                                const float* __restrict__ Pk,
                                                const float* __restrict__ Pv,
                                                unsigned short* __restrict__ q,
                                                unsigned short* __restrict__ kb,
                                                unsigned short* __restrict__ vt,
                                                float* __restrict__ rowsum) {
  __shared__ __align__(16) unsigned short As[128 * 64];
  __shared__ __align__(16) unsigned short Bs[128 * 64];
  const int tid = threadIdx.x;
  const int b = blockIdx.x;

  if (b < 512) {  // ---- q = x·Wq^T, R3-exact ----
    f32x4 acc[4][2] = {};
    const int m0 = (b >> 4) * 128, n0 = (b & 15) * 128;
    gemm_loop8(X, W, m0, n0, DDIM, DDIM, 0, DDIM, As, Bs, acc);
    const int wave = tid >> 6, lane = tid & 63;
    const int quad = lane >> 4, l16 = lane & 15, wm = wave >> 2, wn = wave & 3;
#pragma unroll
    for (int i = 0; i < 4; i++)
#pragma unroll
      for (int j = 0; j < 2; j++)
#pragma unroll
        for (int r = 0; r < 4; r++) {
          int row = m0 + wm * 64 + i * 16 + quad * 4 + r;
          int col = n0 + wn * 32 + j * 16 + l16;
          q[(long)row * DDIM + col] = f2bf(acc[i][j][r]);
        }
    return;
  }
  if (b < 2560) {  // ---- Pk f32 -> bf16, 8 elems/thread ----
    size_t i = (size_t)(b - 512) * 512 + tid;
    const float4* p = (const float4*)(Pk + i * 8);
    float4 a = p[0], c = p[1];
    uint4 o = { pack2(a.x, a.y), pack2(a.z, a.w), pack2(c.x, c.y), pack2(c.z, c.w) };
    *(uint4*)(kb + i * 8) = o;
    return;
  }
  if (b == 4608) {  // ---- zero rowsum ----
    for (int k = tid; k < LDIM; k += 512) rowsum[k] = 0.f;
    return;
  }
  // ---- Pv (T x D) f32 -> Vt (D x T) bf16, 64x64 tile, transpose via As ----
  unsigned short (*tile)[72] = (unsigned short (*)[72])As;  // 64x72 u16 <= As
  const int b2 = b - 2560;
  const int t0 = (b2 & 63) * 64, j0 = (b2 >> 6) * 64;
  const int r = tid >> 4, c4 = (tid & 15) * 4;  // r in 0..31
#pragma unroll
  for (int rr = 0; rr < 64; rr += 32) {
    float4 v = *(const float4*)(Pv + (size_t)(t0 + r + rr) * DDIM + j0 + c4);
    tile[c4 + 0][r + rr] = f2bf(v.x);
    tile[c4 + 1][r + rr] = f2bf(v.y);
    tile[c4 + 2][r + rr] = f2bf(v.z);
    tile[c4 + 3][r + rr] = f2bf(v.w);
  }
  __syncthreads();
  const int jr = tid >> 3, tc = (tid & 7) * 8;  // jr in 0..63
  *(uint4*)(vt + (size_t)(j0 + jr) * TDIM + t0 + tc) = *(const uint4*)&tile[jr][tc];
}

// ------------- K2: banded P = exp(q·Pk^T·scale), rowsums (R3-exact) -------------
__global__ __launch_bounds__(512) void k2_qk(const unsigned short* __restrict__ Q,
                                             const unsigned short* __restrict__ Kb,
                                             unsigned short* __restrict__ P,
                                             float* __restrict__ rowsum,
                                             const int* __restrict__ wptr) {
  const int w = *wptr;
  const int l0 = blockIdx.y * 128, t0 = blockIdx.x * 128;
  int lo = l0 - w + 1; if (lo < 0) lo = 0;
  int hi = l0 + 127 + w - 1; if (hi > TDIM - 1) hi = TDIM - 1;
  if ((int)blockIdx.x < (lo >> 7) || (int)blockIdx.x > (hi >> 7)) return;  // uniform
  __shared__ __align__(16) unsigned short As[128 * 64];
  __shared__ __align__(16) unsigned short Bs[128 * 64];
  f32x4 acc[4][2] = {};
  gemm_loop8(Q, Kb, l0, t0, DDIM, DDIM, 0, DDIM, As, Bs, acc);
  const float scale = 0.022097086912079608f;  // 1/sqrt(2048)
  const int tid = threadIdx.x;
  const int wave = tid >> 6, lane = tid & 63;
  const int quad = lane >> 4, l16 = lane & 15, wm = wave >> 2, wn = wave & 3;
#pragma unroll
  for (int i = 0; i < 4; i++) {
    float rs[4] = {0.f, 0.f, 0.f, 0.f};
#pragma unroll
    for (int j = 0; j < 2; j++)
#pragma unroll
      for (int r = 0; r < 4; r++) {
        int l = l0 + wm * 64 + i * 16 + quad * 4 + r;
        int t = t0 + wn * 32 + j * 16 + l16;
        int dlt = l - t; dlt = dlt < 0 ? -dlt : dlt;
        float e = 0.f;
        // scores ~ N(0,1): no overflow -> max-free softmax is exact math
        if (dlt < w) e = __expf(acc[i][j][r] * scale);
        unsigned short bv = f2bf(e);
        P[(long)l * TDIM + t] = bv;
        rs[r] += __uint_as_float((unsigned)bv << 16);  // sum stored (rounded) values
      }
#pragma unroll
    for (int r = 0; r < 4; ++r) {
      float s = rs[r];
      s += __shfl_xor(s, 1);
      s += __shfl_xor(s, 2);
      s += __shfl_xor(s, 4);
      s += __shfl_xor(s, 8);  // 16 lanes hold this row's 32-col slice
      if (l16 == 0) atomicAdd(&rowsum[l0 + wm * 64 + i * 16 + quad * 4 + r], s);
    }
  }
}

// ---------------- K3: y = (P · Vt^T) / rowsum over band tiles (R3-exact) ----------------
__global__ __launch_bounds__(512) void k3_pv(const unsigned short* __restrict__ P,
                                             const unsigned short* __restrict__ Vt,
                                             const float* __restrict__ rowsum,
                                             float* __restrict__ Y,
                                             const int* __restrict__ wptr) {
  const int w = *wptr;
  const int l0 = blockIdx.y * 128, j0 = blockIdx.x * 128;
  int lo = l0 - w + 1; if (lo < 0) lo = 0;
  int hi = l0 + 127 + w - 1; if (hi > TDIM - 1) hi = TDIM - 1;
  const int kb = (lo >> 7) * 128, ke = ((hi >> 7) + 1) * 128;  // exactly K2's tiles
  __shared__ __align__(16) unsigned short As[128 * 64];
  __shared__ __align__(16) unsigned short Bs[128 * 64];
  f32x4 acc[4][2] = {};
  gemm_loop8(P, Vt, l0, j0, TDIM, TDIM, kb, ke, As, Bs, acc);
  const int tid = threadIdx.x;
  const int wave = tid >> 6, lane = tid & 63;
  const int quad = lane >> 4, l16 = lane & 15, wm = wave >> 2, wn = wave & 3;
#pragma unroll
  for (int i = 0; i < 4; i++)
#pragma unroll
    for (int r = 0; r < 4; r++) {
      const int l = l0 + wm * 64 + i * 16 + quad * 4 + r;
      const float inv = 1.0f / rowsum[l];
#pragma unroll
      for (int j = 0; j < 2; j++)
        Y[(long)l * DDIM + j0 + wn * 32 + j * 16 + l16] = acc[i][j][r] * inv;
    }
}

extern "C" void kernel_launch(void* const* d_in, const int* in_sizes, int n_in,
                              void* d_out, int out_size, void* d_ws, size_t ws_size,
                              hipStream_t stream) {
  const float* x  = (const float*)d_in[0];   // (4096, 2048)
  const float* Wq = (const float*)d_in[1];   // (2048, 2048)
  const float* Pk = (const float*)d_in[2];   // (1, 4096, 2048)
  const float* Pv = (const float*)d_in[3];   // (1, 4096, 2048)
  const int* wptr = (const int*)d_in[4];     // sliding_window_size
  float* Y = (float*)d_out;                  // (1, 4096, 2048) f32

  // ws (u16 elems). P aliases xb+wb (dead after K1). Total ~84 MB.
  unsigned short* base = (unsigned short*)d_ws;
  unsigned short* Pm = base;                          // 4096*4096 [k2/k3]
  unsigned short* xb = base;                          // 4096*2048 (aliases Pm)
  unsigned short* wb = base + (size_t)LDIM * DDIM;    // 2048*2048 (aliases Pm)
  unsigned short* kb = base + (size_t)TDIM * TDIM;    // 4096*2048
  unsigned short* vt = kb + (size_t)TDIM * DDIM;      // 2048*4096
  unsigned short* qb = vt + (size_t)DDIM * TDIM;      // 4096*2048
  float* rowsum = (float*)(qb + (size_t)LDIM * DDIM); // 4096 f32

  k_prep<<<6144, 256, 0, stream>>>(x, Wq, xb, wb);
  k1_fused<<<4609, 512, 0, stream>>>(xb, wb, Pk, Pv, qb, kb, vt, rowsum);
  k2_qk<<<dim3(TDIM / 128, LDIM / 128), 512, 0, stream>>>(qb, kb, Pm, rowsum, wptr);
  k3_pv<<<dim3(DDIM / 128, LDIM / 128), 512, 0, stream>>>(Pm, vt, rowsum, Y, wptr);
}